// Round 1
// baseline (259.399 us; speedup 1.0000x reference)
//
#include <hip/hip_runtime.h>
#include <math.h>

#define CDIM 128
#define HH 128
#define WW 128
#define TH 8
#define TW 16
#define DWSTRIDE 2052   // 128*16 + 4 floats: makes phase-2 b128 reads bank-conflict-free

// ws layout (floats):
//   [0, 9216)        kern: [b][c][9]
//   [9216, 10240)    att:  [b][128]
//   [10240, 26624)   cwT:  [c][o]  (transposed conv_w)

__global__ __launch_bounds__(256) void precompute_kernel(
    const float* __restrict__ altitude,
    const float* __restrict__ W1,
    const float* __restrict__ W2,
    const float* __restrict__ ca_w1,
    const float* __restrict__ ca_w2,
    const float* __restrict__ conv_w,
    float* __restrict__ ws)
{
    int b = blockIdx.x;
    int t = threadIdx.x;
    __shared__ float alt_s[128];
    __shared__ float feat_s[128];
    __shared__ float a1_s[16];

    if (t < 128) alt_s[t] = altitude[b * 128 + t];
    __syncthreads();

    if (t < 128) {
        float s = 0.f;
        const float* wrow = W1 + t * 128;
        for (int j = 0; j < 128; ++j) s += alt_s[j] * wrow[j];
        feat_s[t] = (s >= 0.f) ? s : 0.1f * s;
    } else if (t < 144) {
        int r = t - 128;
        float s = 0.f;
        const float* wrow = ca_w1 + r * 128;
        for (int j = 0; j < 128; ++j) s += alt_s[j] * wrow[j];
        a1_s[r] = (s >= 0.f) ? s : 0.1f * s;
    }
    __syncthreads();

    // generated depthwise kernels: kern[b][m] = sum_i feat[i] * W2[m][i]
    for (int m = t; m < 1152; m += 256) {
        float s = 0.f;
        const float* wrow = W2 + m * 128;
        for (int i = 0; i < 128; ++i) s += feat_s[i] * wrow[i];
        ws[b * 1152 + m] = s;
    }
    // channel attention: att[b][o] = sigmoid(sum_r a1[r] * ca_w2[o][r])
    if (t < 128) {
        float s = 0.f;
        const float* wrow = ca_w2 + t * 16;
        for (int r = 0; r < 16; ++r) s += a1_s[r] * wrow[r];
        ws[9216 + b * 128 + t] = 1.f / (1.f + expf(-s));
    }
    // transpose conv_w -> cwT[c][o] (split across the 8 blocks)
    for (int i = t; i < 2048; i += 256) {
        int idx = b * 2048 + i;
        int c = idx >> 7;
        int o = idx & 127;
        ws[10240 + c * 128 + o] = conv_w[o * 128 + c];
    }
}

__global__ __launch_bounds__(256, 2) void fused_kernel(
    const float* __restrict__ x,
    const float* __restrict__ conv_b,
    const float* __restrict__ ws,
    float* __restrict__ out)
{
    const float* __restrict__ kern_w = ws;
    const float* __restrict__ att_w  = ws + 9216;
    const float* __restrict__ cwT    = ws + 10240;

    int bid = blockIdx.x;
    int b = bid >> 7;          // 128 tiles per batch sample
    int rem = bid & 127;
    int htile = rem >> 3;      // 16 h-tiles
    int wtile = rem & 7;       // 8 w-tiles
    int h0 = htile * TH;
    int w0 = wtile * TW;

    __shared__ float kern_s[1152];
    __shared__ float att_s[128];
    __shared__ float bias_s[128];
    __shared__ float dw_s[8 * DWSTRIDE];   // [pb][c][16] , stride 2052

    int t = threadIdx.x;
    for (int i = t; i < 1152; i += 256) kern_s[i] = kern_w[b * 1152 + i];
    if (t < 128) { att_s[t] = att_w[b * 128 + t]; bias_s[t] = conv_b[t]; }
    __syncthreads();

    const size_t plane = (size_t)HH * WW;
    const float* __restrict__ xb = x + (size_t)b * CDIM * plane;

    // ---------------- Phase 1: depthwise 3x3 + ReLU -> LDS ----------------
    {
        int p   = t & 127;       // pixel within 8x16 tile
        int py  = p >> 4;        // tile row  (== pb of phase 2)
        int pxl = p & 15;        // tile col
        int cbase = (t >> 7) * 64;
        int hy = h0 + py;
        int wx = w0 + pxl;
        bool interior = (h0 >= 1) && (h0 + TH <= 127) && (w0 >= 1) && (w0 + TW <= 127);
        float* dwrow = dw_s + py * DWSTRIDE + pxl;

        if (interior) {
            for (int i = 0; i < 64; ++i) {
                int c = cbase + i;
                const float* q  = xb + (size_t)c * plane + (hy - 1) * WW + (wx - 1);
                const float* kp = kern_s + c * 9;
                float s = q[0]      * kp[0] + q[1]        * kp[1] + q[2]        * kp[2]
                        + q[WW]     * kp[3] + q[WW + 1]   * kp[4] + q[WW + 2]   * kp[5]
                        + q[2 * WW] * kp[6] + q[2*WW + 1] * kp[7] + q[2*WW + 2] * kp[8];
                dwrow[c * 16] = fmaxf(s, 0.f);
            }
        } else {
            for (int i = 0; i < 64; ++i) {
                int c = cbase + i;
                const float* q  = xb + (size_t)c * plane;
                const float* kp = kern_s + c * 9;
                float s = 0.f;
                #pragma unroll
                for (int dy = 0; dy < 3; ++dy) {
                    int yy = hy + dy - 1;
                    if ((unsigned)yy < 128u) {
                        const float* row = q + yy * WW;
                        #pragma unroll
                        for (int dx = 0; dx < 3; ++dx) {
                            int xx = wx + dx - 1;
                            if ((unsigned)xx < 128u) s += row[xx] * kp[dy * 3 + dx];
                        }
                    }
                }
                dwrow[c * 16] = fmaxf(s, 0.f);
            }
        }
    }
    __syncthreads();

    // ---------------- Phase 2: 1x1 conv (channel mix) + bias + residual ----------------
    {
        int ob = t >> 3;         // 32 o-blocks of 4 output channels
        int o0 = ob * 4;
        int pb = t & 7;          // tile row
        const float* dwr = dw_s + pb * DWSTRIDE;

        float acc[4][16];
        #pragma unroll
        for (int i = 0; i < 4; ++i)
            #pragma unroll
            for (int j = 0; j < 16; ++j) acc[i][j] = 0.f;

        #pragma unroll 2
        for (int c = 0; c < 128; ++c) {
            float4 wv = *(const float4*)(cwT + c * 128 + o0);
            float4 d0 = *(const float4*)(dwr + c * 16 + 0);
            float4 d1 = *(const float4*)(dwr + c * 16 + 4);
            float4 d2 = *(const float4*)(dwr + c * 16 + 8);
            float4 d3 = *(const float4*)(dwr + c * 16 + 12);
            float dv[16];
            dv[0]=d0.x; dv[1]=d0.y; dv[2]=d0.z;  dv[3]=d0.w;
            dv[4]=d1.x; dv[5]=d1.y; dv[6]=d1.z;  dv[7]=d1.w;
            dv[8]=d2.x; dv[9]=d2.y; dv[10]=d2.z; dv[11]=d2.w;
            dv[12]=d3.x; dv[13]=d3.y; dv[14]=d3.z; dv[15]=d3.w;
            float wr[4] = {wv.x, wv.y, wv.z, wv.w};
            #pragma unroll
            for (int i = 0; i < 4; ++i)
                #pragma unroll
                for (int j = 0; j < 16; ++j)
                    acc[i][j] = fmaf(wr[i], dv[j], acc[i][j]);
        }

        int hh = h0 + pb;
        #pragma unroll
        for (int i = 0; i < 4; ++i) {
            int o = o0 + i;
            float a  = att_s[o];
            float bi = bias_s[o];
            size_t off = (size_t)(b * CDIM + o) * plane + (size_t)hh * WW + w0;
            const float* xr = x + off;
            float* orow = out + off;
            #pragma unroll
            for (int j = 0; j < 16; j += 4) {
                float4 xv = *(const float4*)(xr + j);
                float4 ov;
                ov.x = acc[i][j + 0] + bi + xv.x * a;
                ov.y = acc[i][j + 1] + bi + xv.y * a;
                ov.z = acc[i][j + 2] + bi + xv.z * a;
                ov.w = acc[i][j + 3] + bi + xv.w * a;
                *(float4*)(orow + j) = ov;
            }
        }
    }
}

extern "C" void kernel_launch(void* const* d_in, const int* in_sizes, int n_in,
                              void* d_out, int out_size, void* d_ws, size_t ws_size,
                              hipStream_t stream) {
    const float* x        = (const float*)d_in[0];
    const float* altitude = (const float*)d_in[1];
    const float* W1       = (const float*)d_in[2];
    const float* W2       = (const float*)d_in[3];
    const float* conv_w   = (const float*)d_in[4];
    const float* conv_b   = (const float*)d_in[5];
    const float* ca_w1    = (const float*)d_in[6];
    const float* ca_w2    = (const float*)d_in[7];
    float* out = (float*)d_out;
    float* ws  = (float*)d_ws;

    hipLaunchKernelGGL(precompute_kernel, dim3(8), dim3(256), 0, stream,
                       altitude, W1, W2, ca_w1, ca_w2, conv_w, ws);
    hipLaunchKernelGGL(fused_kernel, dim3(8 * 16 * 8), dim3(256), 0, stream,
                       x, conv_b, ws, out);
}

// Round 2
// 91.291 us; speedup vs baseline: 2.8414x; 2.8414x over previous
//
#include <hip/hip_runtime.h>
#include <math.h>

typedef __attribute__((ext_vector_type(8))) __bf16 bf16x8;
typedef __attribute__((ext_vector_type(4))) float f32x4;

#define PLANE 16384
#define WWIDTH 128
#define CD 128

// ws float layout:
//   [0, 9216)      kern [b][c][9]          (fp32)
//   [9216, 10240)  att  [b][128]           (fp32)
//   [10240, 18432) Wfrag 16384 ushorts: [os(8)][kc(4)][lane(64)][j(8)]  (bf16)

__global__ __launch_bounds__(256) void precompute_kernel(
    const float* __restrict__ altitude,
    const float* __restrict__ W1,
    const float* __restrict__ W2,
    const float* __restrict__ ca_w1,
    const float* __restrict__ ca_w2,
    const float* __restrict__ conv_w,
    float* __restrict__ ws)
{
    int b = blockIdx.x;
    int t = threadIdx.x;
    __shared__ float alt_s[128];
    __shared__ float feat_s[128];
    __shared__ float a1_s[16];

    if (t < 128) alt_s[t] = altitude[b * 128 + t];
    __syncthreads();

    if (t < 128) {
        float s = 0.f;
        const float* wrow = W1 + t * 128;
        for (int j = 0; j < 128; ++j) s += alt_s[j] * wrow[j];
        feat_s[t] = (s >= 0.f) ? s : 0.1f * s;
    } else if (t < 144) {
        int r = t - 128;
        float s = 0.f;
        const float* wrow = ca_w1 + r * 128;
        for (int j = 0; j < 128; ++j) s += alt_s[j] * wrow[j];
        a1_s[r] = (s >= 0.f) ? s : 0.1f * s;
    }
    __syncthreads();

    // generated depthwise kernels: kern[b][m] = sum_i feat[i] * W2[m][i]
    for (int m = t; m < 1152; m += 256) {
        float s = 0.f;
        const float* wrow = W2 + m * 128;
        for (int i = 0; i < 128; ++i) s += feat_s[i] * wrow[i];
        ws[b * 1152 + m] = s;
    }
    // channel attention
    if (t < 128) {
        float s = 0.f;
        const float* wrow = ca_w2 + t * 16;
        for (int r = 0; r < 16; ++r) s += a1_s[r] * wrow[r];
        ws[9216 + b * 128 + t] = 1.f / (1.f + expf(-s));
    }
    // conv_w -> bf16 MFMA A-fragments. os index = this block's b (8 blocks, 8 os).
    // A[i=o][k=c]; lane l holds A[os*16 + (l&15)][kc*32 + 8*(l>>4) + j], j=0..7
    {
        int kc   = t >> 6;
        int lane = t & 63;
        int o  = b * 16 + (lane & 15);
        int cb = kc * 32 + 8 * (lane >> 4);
        bf16x8 v;
        #pragma unroll
        for (int j = 0; j < 8; ++j)
            v[j] = (__bf16)conv_w[o * 128 + cb + j];
        ushort* wf = (ushort*)(ws + 10240);
        *reinterpret_cast<bf16x8*>(wf + ((size_t)(b * 4 + kc) * 64 + lane) * 8) = v;
    }
}

__global__ __launch_bounds__(256, 4) void fused_kernel(
    const float* __restrict__ x,
    const float* __restrict__ conv_b,
    const float* __restrict__ ws,
    float* __restrict__ out)
{
    const float* __restrict__ kern_w = ws;
    const float* __restrict__ att_w  = ws + 9216;
    const ushort* __restrict__ wfrag = (const ushort*)(ws + 10240);

    // XCD swizzle: b = bid&7 so each XCD streams one batch image
    int bid = blockIdx.x;
    int b      = bid & 7;
    int within = bid >> 3;      // 0..255
    int h      = within >> 1;   // row 0..127
    int w0     = (within & 1) * 64;

    __shared__ __align__(16) ushort dwT[64 * 136];  // [w][c] bf16, stride 136
    __shared__ float kern_s[1152];
    __shared__ float att_s[128];
    __shared__ float bias_s[128];

    int t = threadIdx.x;
    for (int i = t; i < 1152; i += 256) kern_s[i] = kern_w[b * 1152 + i];
    if (t < 128) { att_s[t] = att_w[b * 128 + t]; bias_s[t] = conv_b[t]; }
    __syncthreads();

    const float* __restrict__ xb = x + (size_t)b * CD * PLANE;

    // ---------------- Phase 1: depthwise 3x3 + ReLU -> bf16 dwT[w][c] ----------------
    {
        int wl   = t & 63;       // local pixel col
        int cgrp = t >> 6;       // 0..3 (uniform per wave)
        int gw   = w0 + wl;
        float lm = (gw > 0)   ? 1.f : 0.f;
        float rm = (gw < 127) ? 1.f : 0.f;
        int wlc = (gw > 0)   ? -1 : 0;
        int wrc = (gw < 127) ?  1 : 0;
        bool hasT = (h > 0), hasB = (h < 127);
        const float* qbase = xb + h * WWIDTH + gw;

        bf16x8 buf;
        #pragma unroll
        for (int i = 0; i < 32; ++i) {
            int c = cgrp * 32 + i;
            const float* q  = qbase + (size_t)c * PLANE;
            const float* kp = kern_s + c * 9;
            float k3 = kp[3] * lm, k4 = kp[4], k5 = kp[5] * rm;
            float s = q[wlc] * k3 + q[0] * k4 + q[wrc] * k5;
            if (hasT) {
                float k0 = kp[0] * lm, k1 = kp[1], k2 = kp[2] * rm;
                const float* qt = q - WWIDTH;
                s += qt[wlc] * k0 + qt[0] * k1 + qt[wrc] * k2;
            }
            if (hasB) {
                float k6 = kp[6] * lm, k7 = kp[7], k8 = kp[8] * rm;
                const float* qb = q + WWIDTH;
                s += qb[wlc] * k6 + qb[0] * k7 + qb[wrc] * k8;
            }
            buf[i & 7] = (__bf16)fmaxf(s, 0.f);
            if ((i & 7) == 7)
                *reinterpret_cast<bf16x8*>(&dwT[wl * 136 + (c - 7)]) = buf;
        }
    }
    __syncthreads();

    // ---------------- Phase 2: 1x1 conv via MFMA + bias + residual ----------------
    {
        int wid  = t >> 6;   // wave 0..3 -> o range [wid*32, wid*32+32)
        int lane = t & 63;

        // A fragments from L2-resident precomputed table (coalesced 16B/lane)
        bf16x8 af[2][4];
        #pragma unroll
        for (int os = 0; os < 2; ++os) {
            int osg = wid * 2 + os;
            #pragma unroll
            for (int kc = 0; kc < 4; ++kc)
                af[os][kc] = *reinterpret_cast<const bf16x8*>(
                    wfrag + ((size_t)(osg * 4 + kc) * 64 + lane) * 8);
        }

        f32x4 acc[2][4];
        #pragma unroll
        for (int os = 0; os < 2; ++os)
            #pragma unroll
            for (int ps = 0; ps < 4; ++ps)
                acc[os][ps] = (f32x4){0.f, 0.f, 0.f, 0.f};

        #pragma unroll
        for (int ps = 0; ps < 4; ++ps) {
            #pragma unroll
            for (int kc = 0; kc < 4; ++kc) {
                // B[k=c][n=w]: lane holds 8 contiguous c at fixed w
                bf16x8 bf = *reinterpret_cast<const bf16x8*>(
                    &dwT[(ps * 16 + (lane & 15)) * 136 + kc * 32 + 8 * (lane >> 4)]);
                acc[0][ps] = __builtin_amdgcn_mfma_f32_16x16x32_bf16(af[0][kc], bf, acc[0][ps], 0, 0, 0);
                acc[1][ps] = __builtin_amdgcn_mfma_f32_16x16x32_bf16(af[1][kc], bf, acc[1][ps], 0, 0, 0);
            }
        }

        // epilogue: D layout col = lane&15 (w), row = (lane>>4)*4 + reg (o)
        size_t obase = (size_t)b * CD * PLANE;
        #pragma unroll
        for (int os = 0; os < 2; ++os) {
            int ob = wid * 32 + os * 16 + (lane >> 4) * 4;
            #pragma unroll
            for (int j = 0; j < 4; ++j) {
                int o = ob + j;
                float bi = bias_s[o];
                float at = att_s[o];
                size_t rowoff = (size_t)o * PLANE + h * WWIDTH + w0 + (lane & 15);
                const float* xrow = xb + rowoff;
                float* orow = out + obase + rowoff;
                #pragma unroll
                for (int ps = 0; ps < 4; ++ps)
                    orow[ps * 16] = acc[os][ps][j] + bi + xrow[ps * 16] * at;
            }
        }
    }
}

extern "C" void kernel_launch(void* const* d_in, const int* in_sizes, int n_in,
                              void* d_out, int out_size, void* d_ws, size_t ws_size,
                              hipStream_t stream) {
    (void)in_sizes; (void)n_in; (void)out_size; (void)ws_size;
    const float* x        = (const float*)d_in[0];
    const float* altitude = (const float*)d_in[1];
    const float* W1       = (const float*)d_in[2];
    const float* W2       = (const float*)d_in[3];
    const float* conv_w   = (const float*)d_in[4];
    const float* conv_b   = (const float*)d_in[5];
    const float* ca_w1    = (const float*)d_in[6];
    const float* ca_w2    = (const float*)d_in[7];
    float* out = (float*)d_out;
    float* ws  = (float*)d_ws;

    hipLaunchKernelGGL(precompute_kernel, dim3(8), dim3(256), 0, stream,
                       altitude, W1, W2, ca_w1, ca_w2, conv_w, ws);
    hipLaunchKernelGGL(fused_kernel, dim3(2048), dim3(256), 0, stream,
                       x, conv_b, ws, out);
}